// Round 4
// baseline (125.886 us; speedup 1.0000x reference)
//
#include <hip/hip_runtime.h>

// 22-qubit QAOA state-vector sim. Register/shfl/LDS-transpose butterflies,
// fp16-packed state (computed in f32; amplitudes ~2^-11, fp16 rel err 5e-4,
// output threshold 1e-2 -> safe). Butterfly c = cb*c + i*sb*partner is
// symmetric, so each stage runs where the partner lives.
//   K1: init + phase1 + layer1 bits 0-12   (contiguous blocks)
//   K2: layer1 bits 13-21 + phase2 + layer2 bits 13-21
//   K3: layer2 bits 0-12 + fused |c|^2*hS reduce -> one atomicAdd per block
// State in d_ws: half2 per amplitude (16 MB). HBM total ~112 MB.
// R3 bug fix: K2 LDS array was sized 1024 words instead of GRP*HI=8192 ->
// OOB transpose -> absmax 0.42. Restored HI and correct size.

#define NTOT    (1u << 22)
#define LO_BITS 13
#define HI_BITS 9
#define LO      (1u << LO_BITS)   // 8192
#define HI      (1u << HI_BITS)   // 512
#define GRP     16                // lo-columns per K2 block
#define TPB     512
#define R       16                // complex elements per thread

typedef __fp16 h2_t __attribute__((ext_vector_type(2)));
union PkU { unsigned u; h2_t h; };

__device__ __forceinline__ unsigned pk(float x, float y) {
    PkU p; p.h = __builtin_amdgcn_cvt_pkrtz(x, y); return p.u;
}
__device__ __forceinline__ float2 unpk(unsigned v) {
    PkU p; p.u = v; return make_float2((float)p.h.x, (float)p.h.y);
}

// register butterfly on register-index bit MASK (f32)
#define REGSTAGE(MASK, CB, SB) {                                  \
    _Pragma("unroll")                                             \
    for (int r0 = 0; r0 < R; ++r0) {                              \
        if ((r0 & (MASK)) == 0) {                                 \
            const int r1 = r0 | (MASK);                           \
            float t0r = re[r0], t0i = im[r0];                     \
            float t1r = re[r1], t1i = im[r1];                     \
            re[r0] = (CB) * t0r - (SB) * t1i;                     \
            im[r0] = (CB) * t0i + (SB) * t1r;                     \
            re[r1] = (CB) * t1r - (SB) * t0i;                     \
            im[r1] = (CB) * t1i + (SB) * t0r;                     \
        } } }

// cross-lane butterfly: ONE packed-half2 shuffle per element (partner is
// scaled by sb~0.01, so fp16 partner rounding is negligible)
#define SHFLSTAGE(MASK, CB, SB) {                                 \
    _Pragma("unroll")                                             \
    for (int r = 0; r < R; ++r) {                                 \
        unsigned pv = (unsigned)__shfl_xor((int)pk(re[r], im[r]), (MASK), 64); \
        float2 p = unpk(pv);                                      \
        float tr = re[r], ti = im[r];                             \
        re[r] = (CB) * tr - (SB) * p.y;                           \
        im[r] = (CB) * ti + (SB) * p.x;                           \
    } }

// ---------------- K1: init + phase1 + layer-1 bits 0-12 ----------------
__global__ __launch_bounds__(TPB, 4) void k_init_low(
    const float* __restrict__ h, const float* __restrict__ gam,
    const float* __restrict__ bet, unsigned* __restrict__ st,
    float* __restrict__ out)
{
    __shared__ unsigned sC[LO];   // 32 KB
    const float g1 = gam[0];
    const float cb = __cosf(bet[0]), sb = __sinf(bet[0]);
    const unsigned t = threadIdx.x, lane = t & 63u, wave = t >> 6;
    const size_t base = (size_t)blockIdx.x * LO;
    float re[R], im[R];

    if (blockIdx.x == 0 && t == 0) out[0] = 0.f;   // K3 accumulates later

    // elem i = r*512 + t : bits0-5=lane, bits6-8=wave, bits9-12=r
    #pragma unroll
    for (int r = 0; r < R; ++r) {
        float s, c;
        __sincosf(g1 * h[base + (unsigned)r * TPB + t], &s, &c);
        re[r] = c * 0x1p-11f;
        im[r] = s * 0x1p-11f;
    }
    REGSTAGE(1, cb, sb)  REGSTAGE(2, cb, sb)      // bits 9,10
    REGSTAGE(4, cb, sb)  REGSTAGE(8, cb, sb)      // bits 11,12
    SHFLSTAGE(1,  cb, sb) SHFLSTAGE(2,  cb, sb)   // bits 0,1
    SHFLSTAGE(4,  cb, sb) SHFLSTAGE(8,  cb, sb)   // bits 2,3
    SHFLSTAGE(16, cb, sb) SHFLSTAGE(32, cb, sb)   // bits 4,5
    // transpose: wave bits 6-8 -> register position
    #pragma unroll
    for (int r = 0; r < R; ++r) sC[(unsigned)r * TPB + t] = pk(re[r], im[r]);
    __syncthreads();
    #pragma unroll
    for (int r = 0; r < R; ++r) {
        unsigned j = lane | ((unsigned)(r & 7) << 6) | (wave << 9) | ((unsigned)(r >> 3) << 12);
        float2 v = unpk(sC[j]); re[r] = v.x; im[r] = v.y;
    }
    REGSTAGE(1, cb, sb)  REGSTAGE(2, cb, sb)  REGSTAGE(4, cb, sb)   // bits 6,7,8
    #pragma unroll
    for (int r = 0; r < R; ++r) {
        unsigned j = lane | ((unsigned)(r & 7) << 6) | (wave << 9) | ((unsigned)(r >> 3) << 12);
        st[base + j] = pk(re[r], im[r]);
    }
}

// -------- K2: layer-1 bits 13-21 + phase2 + layer-2 bits 13-21 --------
__global__ __launch_bounds__(TPB, 4) void k_high(
    const float* __restrict__ h, const float* __restrict__ gam,
    const float* __restrict__ bet, unsigned* __restrict__ st)
{
    __shared__ unsigned sC[GRP * HI];   // 8192 words, 32 KB
    const float g2  = gam[1];
    const float cb1 = __cosf(bet[0]), sb1 = __sinf(bet[0]);
    const float cb2 = __cosf(bet[1]), sb2 = __sinf(bet[1]);
    const unsigned t = threadIdx.x, lane = t & 63u, wave = t >> 6;
    const unsigned lo0 = blockIdx.x * GRP;
    const unsigned g   = lane & (GRP - 1);   // lo offset (coalescing)
    const unsigned h01 = lane >> 4;          // hi bits 0-1
    float re[R], im[R];

    // mapping A: hi = h01 | wave<<2 | r<<5
    #pragma unroll
    for (int r = 0; r < R; ++r) {
        unsigned hi = h01 | (wave << 2) | ((unsigned)r << 5);
        float2 v = unpk(st[(size_t)hi * LO + lo0 + g]);
        re[r] = v.x; im[r] = v.y;
    }
    // layer1: hi bits 5-8 (reg), hi bits 0-1 (lane bits 4,5)
    REGSTAGE(1, cb1, sb1)  REGSTAGE(2, cb1, sb1)
    REGSTAGE(4, cb1, sb1)  REGSTAGE(8, cb1, sb1)
    SHFLSTAGE(16, cb1, sb1) SHFLSTAGE(32, cb1, sb1)
    // transpose A->B: B has hi = h01 | (r&7)<<2 | wave<<5 | (r>>3)<<8
    #pragma unroll
    for (int r = 0; r < R; ++r) {
        unsigned li = g | (h01 << 4) | (wave << 6) | ((unsigned)r << 9);
        sC[li] = pk(re[r], im[r]);
    }
    __syncthreads();
    #pragma unroll
    for (int r = 0; r < R; ++r) {
        unsigned li = g | (h01 << 4) | ((unsigned)(r & 7) << 6) | (wave << 9) | ((unsigned)(r >> 3) << 12);
        float2 v = unpk(sC[li]); re[r] = v.x; im[r] = v.y;
    }
    REGSTAGE(1, cb1, sb1)  REGSTAGE(2, cb1, sb1)  REGSTAGE(4, cb1, sb1)  // hi bits 2,3,4
    // phase2 (layer-1 complete for these elements; low bits were done in K1)
    #pragma unroll
    for (int r = 0; r < R; ++r) {
        unsigned hi = h01 | ((unsigned)(r & 7) << 2) | (wave << 5) | ((unsigned)(r >> 3) << 8);
        float s, c;
        __sincosf(g2 * h[(size_t)hi * LO + lo0 + g], &s, &c);
        float tr = re[r], ti = im[r];
        re[r] = tr * c - ti * s;
        im[r] = tr * s + ti * c;
    }
    // layer2 at B: hi bits 2,3,4,8 (reg), hi bits 0,1 (lane)
    REGSTAGE(1, cb2, sb2)  REGSTAGE(2, cb2, sb2)
    REGSTAGE(4, cb2, sb2)  REGSTAGE(8, cb2, sb2)
    SHFLSTAGE(16, cb2, sb2) SHFLSTAGE(32, cb2, sb2)
    // transpose B->A, then hi bits 5,6,7 (reg)
    __syncthreads();
    #pragma unroll
    for (int r = 0; r < R; ++r) {
        unsigned li = g | (h01 << 4) | ((unsigned)(r & 7) << 6) | (wave << 9) | ((unsigned)(r >> 3) << 12);
        sC[li] = pk(re[r], im[r]);
    }
    __syncthreads();
    #pragma unroll
    for (int r = 0; r < R; ++r) {
        unsigned li = g | (h01 << 4) | (wave << 6) | ((unsigned)r << 9);
        float2 v = unpk(sC[li]); re[r] = v.x; im[r] = v.y;
    }
    REGSTAGE(1, cb2, sb2)  REGSTAGE(2, cb2, sb2)  REGSTAGE(4, cb2, sb2)  // hi bits 5,6,7
    #pragma unroll
    for (int r = 0; r < R; ++r) {
        unsigned hi = h01 | (wave << 2) | ((unsigned)r << 5);
        st[(size_t)hi * LO + lo0 + g] = pk(re[r], im[r]);
    }
}

// -------- K3: layer-2 bits 0-12 + fused |c|^2 * hS -> atomicAdd --------
__global__ __launch_bounds__(TPB, 4) void k_low2(
    const float* __restrict__ hS, const float* __restrict__ bet,
    const unsigned* __restrict__ st, float* __restrict__ out)
{
    __shared__ unsigned sC[LO];
    __shared__ float wsum[TPB / 64];
    const float cb = __cosf(bet[1]), sb = __sinf(bet[1]);
    const unsigned t = threadIdx.x, lane = t & 63u, wave = t >> 6;
    const size_t base = (size_t)blockIdx.x * LO;
    float re[R], im[R];

    #pragma unroll
    for (int r = 0; r < R; ++r) {
        float2 v = unpk(st[base + (unsigned)r * TPB + t]);
        re[r] = v.x; im[r] = v.y;
    }
    REGSTAGE(1, cb, sb)  REGSTAGE(2, cb, sb)
    REGSTAGE(4, cb, sb)  REGSTAGE(8, cb, sb)
    SHFLSTAGE(1,  cb, sb) SHFLSTAGE(2,  cb, sb)
    SHFLSTAGE(4,  cb, sb) SHFLSTAGE(8,  cb, sb)
    SHFLSTAGE(16, cb, sb) SHFLSTAGE(32, cb, sb)
    #pragma unroll
    for (int r = 0; r < R; ++r) sC[(unsigned)r * TPB + t] = pk(re[r], im[r]);
    __syncthreads();
    #pragma unroll
    for (int r = 0; r < R; ++r) {
        unsigned j = lane | ((unsigned)(r & 7) << 6) | (wave << 9) | ((unsigned)(r >> 3) << 12);
        float2 v = unpk(sC[j]); re[r] = v.x; im[r] = v.y;
    }
    REGSTAGE(1, cb, sb)  REGSTAGE(2, cb, sb)  REGSTAGE(4, cb, sb)
    float acc = 0.f;
    #pragma unroll
    for (int r = 0; r < R; ++r) {
        unsigned j = lane | ((unsigned)(r & 7) << 6) | (wave << 9) | ((unsigned)(r >> 3) << 12);
        acc = fmaf(re[r] * re[r] + im[r] * im[r], hS[base + j], acc);
    }
    #pragma unroll
    for (int off = 32; off >= 1; off >>= 1)
        acc += __shfl_down(acc, off, 64);
    if (lane == 0) wsum[wave] = acc;
    __syncthreads();
    if (t == 0) {
        float s = 0.f;
        #pragma unroll
        for (int w = 0; w < TPB / 64; ++w) s += wsum[w];
        unsafeAtomicAdd(out, s);   // native global_atomic_add_f32
    }
}

extern "C" void kernel_launch(void* const* d_in, const int* in_sizes, int n_in,
                              void* d_out, int out_size, void* d_ws, size_t ws_size,
                              hipStream_t stream)
{
    (void)in_sizes; (void)n_in; (void)out_size; (void)ws_size;
    const float* h   = (const float*)d_in[0];
    const float* hS  = (const float*)d_in[1];
    const float* gam = (const float*)d_in[2];
    const float* bet = (const float*)d_in[3];
    unsigned* st = (unsigned*)d_ws;       // 16 MB half2 state
    float* out   = (float*)d_out;

    k_init_low<<<dim3(NTOT / LO), dim3(TPB), 0, stream>>>(h, gam, bet, st, out);
    k_high    <<<dim3(LO / GRP),  dim3(TPB), 0, stream>>>(h, gam, bet, st);
    k_low2    <<<dim3(NTOT / LO), dim3(TPB), 0, stream>>>(hS, bet, st, out);
}

// Round 5
// 120.857 us; speedup vs baseline: 1.0416x; 1.0416x over previous
//
#include <hip/hip_runtime.h>

// 22-qubit QAOA state-vector sim. Register/shfl/LDS-transpose butterflies,
// fp16-packed state (computed in f32). Butterfly c = cb*c + i*sb*partner is
// symmetric, so each stage runs where the partner lives.
//   K1: init + phase1 + layer1 bits 0-12   (contiguous blocks)
//   K2: layer1 bits 13-21 + phase2 + layer2 bits 13-21  (strided)
//   K3: layer2 bits 0-12 + fused |c|^2*hS reduce -> one atomicAdd per block
// R5: K2 rebuilt for access granularity — GRP=32 lo-columns (128B segments
// for half2 state and fp32 h, vs 64B in R4), TPB=1024, R=16, 64KB LDS,
// grid=256 (1 block/CU). R4's fp16 change was neutral because 64B segments
// halved DRAM efficiency, cancelling the byte reduction.

#define NTOT    (1u << 22)
#define LO_BITS 13
#define HI_BITS 9
#define LO      (1u << LO_BITS)   // 8192
#define HI      (1u << HI_BITS)   // 512
#define GRP     32                // lo-columns per K2 block (128B segments)
#define TPB     512
#define TPB2    1024
#define R       16                // complex elements per thread

typedef __fp16 h2_t __attribute__((ext_vector_type(2)));
union PkU { unsigned u; h2_t h; };

__device__ __forceinline__ unsigned pk(float x, float y) {
    PkU p; p.h = __builtin_amdgcn_cvt_pkrtz(x, y); return p.u;
}
__device__ __forceinline__ float2 unpk(unsigned v) {
    PkU p; p.u = v; return make_float2((float)p.h.x, (float)p.h.y);
}

// register butterfly on register-index bit MASK (f32)
#define REGSTAGE(MASK, CB, SB) {                                  \
    _Pragma("unroll")                                             \
    for (int r0 = 0; r0 < R; ++r0) {                              \
        if ((r0 & (MASK)) == 0) {                                 \
            const int r1 = r0 | (MASK);                           \
            float t0r = re[r0], t0i = im[r0];                     \
            float t1r = re[r1], t1i = im[r1];                     \
            re[r0] = (CB) * t0r - (SB) * t1i;                     \
            im[r0] = (CB) * t0i + (SB) * t1r;                     \
            re[r1] = (CB) * t1r - (SB) * t0i;                     \
            im[r1] = (CB) * t1i + (SB) * t0r;                     \
        } } }

// cross-lane butterfly: ONE packed-half2 shuffle per element
#define SHFLSTAGE(MASK, CB, SB) {                                 \
    _Pragma("unroll")                                             \
    for (int r = 0; r < R; ++r) {                                 \
        unsigned pv = (unsigned)__shfl_xor((int)pk(re[r], im[r]), (MASK), 64); \
        float2 p = unpk(pv);                                      \
        float tr = re[r], ti = im[r];                             \
        re[r] = (CB) * tr - (SB) * p.y;                           \
        im[r] = (CB) * ti + (SB) * p.x;                           \
    } }

// ---------------- K1: init + phase1 + layer-1 bits 0-12 ----------------
__global__ __launch_bounds__(TPB, 4) void k_init_low(
    const float* __restrict__ h, const float* __restrict__ gam,
    const float* __restrict__ bet, unsigned* __restrict__ st,
    float* __restrict__ out)
{
    __shared__ unsigned sC[LO];   // 32 KB
    const float g1 = gam[0];
    const float cb = __cosf(bet[0]), sb = __sinf(bet[0]);
    const unsigned t = threadIdx.x, lane = t & 63u, wave = t >> 6;
    const size_t base = (size_t)blockIdx.x * LO;
    float re[R], im[R];

    if (blockIdx.x == 0 && t == 0) out[0] = 0.f;   // K3 accumulates later

    // elem i = r*512 + t : bits0-5=lane, bits6-8=wave, bits9-12=r
    #pragma unroll
    for (int r = 0; r < R; ++r) {
        float s, c;
        __sincosf(g1 * h[base + (unsigned)r * TPB + t], &s, &c);
        re[r] = c * 0x1p-11f;
        im[r] = s * 0x1p-11f;
    }
    REGSTAGE(1, cb, sb)  REGSTAGE(2, cb, sb)      // bits 9,10
    REGSTAGE(4, cb, sb)  REGSTAGE(8, cb, sb)      // bits 11,12
    SHFLSTAGE(1,  cb, sb) SHFLSTAGE(2,  cb, sb)   // bits 0,1
    SHFLSTAGE(4,  cb, sb) SHFLSTAGE(8,  cb, sb)   // bits 2,3
    SHFLSTAGE(16, cb, sb) SHFLSTAGE(32, cb, sb)   // bits 4,5
    // transpose: wave bits 6-8 -> register position
    #pragma unroll
    for (int r = 0; r < R; ++r) sC[(unsigned)r * TPB + t] = pk(re[r], im[r]);
    __syncthreads();
    #pragma unroll
    for (int r = 0; r < R; ++r) {
        unsigned j = lane | ((unsigned)(r & 7) << 6) | (wave << 9) | ((unsigned)(r >> 3) << 12);
        float2 v = unpk(sC[j]); re[r] = v.x; im[r] = v.y;
    }
    REGSTAGE(1, cb, sb)  REGSTAGE(2, cb, sb)  REGSTAGE(4, cb, sb)   // bits 6,7,8
    #pragma unroll
    for (int r = 0; r < R; ++r) {
        unsigned j = lane | ((unsigned)(r & 7) << 6) | (wave << 9) | ((unsigned)(r >> 3) << 12);
        st[base + j] = pk(re[r], im[r]);
    }
}

// -------- K2: layer-1 bits 13-21 + phase2 + layer-2 bits 13-21 --------
// TPB2=1024: lane = g(5 lo bits)|h0(hi bit0); wave w(4) ; reg r(4).
// mapping A: hi = h0 | w<<1 | r<<5   (r = hi bits 5-8)
// mapping B: hi = h0 | r<<1 | w<<5   (r = hi bits 1-4)
__global__ __launch_bounds__(TPB2, 4) void k_high(
    const float* __restrict__ h, const float* __restrict__ gam,
    const float* __restrict__ bet, unsigned* __restrict__ st)
{
    __shared__ unsigned sC[GRP * HI];   // 16384 words, 64 KB
    const float g2  = gam[1];
    const float cb1 = __cosf(bet[0]), sb1 = __sinf(bet[0]);
    const float cb2 = __cosf(bet[1]), sb2 = __sinf(bet[1]);
    const unsigned t = threadIdx.x, lane = t & 63u, w = t >> 6;  // w: 0..15
    const unsigned g  = lane & 31u;   // lo offset within group (coalescing)
    const unsigned h0 = lane >> 5;    // hi bit 0
    const unsigned lo0 = blockIdx.x * GRP;
    float re[R], im[R];

    // load at mapping A: 32 lanes x 4B = 128B segments
    #pragma unroll
    for (int r = 0; r < R; ++r) {
        unsigned hi = h0 | (w << 1) | ((unsigned)r << 5);
        float2 v = unpk(st[(size_t)hi * LO + lo0 + g]);
        re[r] = v.x; im[r] = v.y;
    }
    // layer1: hi bits 5-8 (reg), hi bit 0 (lane bit 5)
    REGSTAGE(1, cb1, sb1)  REGSTAGE(2, cb1, sb1)
    REGSTAGE(4, cb1, sb1)  REGSTAGE(8, cb1, sb1)
    SHFLSTAGE(32, cb1, sb1)
    // T1: A -> B  (LDS index = g | hi<<5; 64-consecutive-word waves)
    #pragma unroll
    for (int r = 0; r < R; ++r)
        sC[g | (h0 << 5) | (w << 6) | ((unsigned)r << 10)] = pk(re[r], im[r]);
    __syncthreads();
    #pragma unroll
    for (int r = 0; r < R; ++r) {
        float2 v = unpk(sC[g | (h0 << 5) | ((unsigned)r << 6) | (w << 10)]);
        re[r] = v.x; im[r] = v.y;
    }
    REGSTAGE(1, cb1, sb1)  REGSTAGE(2, cb1, sb1)
    REGSTAGE(4, cb1, sb1)  REGSTAGE(8, cb1, sb1)   // hi bits 1-4; layer1 done
    // phase2 (h strided read: 128B segments, L2/L3-warm from K1)
    #pragma unroll
    for (int r = 0; r < R; ++r) {
        unsigned hi = h0 | ((unsigned)r << 1) | (w << 5);
        float s, c;
        __sincosf(g2 * h[(size_t)hi * LO + lo0 + g], &s, &c);
        float tr = re[r], ti = im[r];
        re[r] = tr * c - ti * s;
        im[r] = tr * s + ti * c;
    }
    // layer2 at B: hi bits 1-4 (reg), hi bit 0 (lane)
    REGSTAGE(1, cb2, sb2)  REGSTAGE(2, cb2, sb2)
    REGSTAGE(4, cb2, sb2)  REGSTAGE(8, cb2, sb2)
    SHFLSTAGE(32, cb2, sb2)
    // T2: B -> A
    __syncthreads();
    #pragma unroll
    for (int r = 0; r < R; ++r)
        sC[g | (h0 << 5) | ((unsigned)r << 6) | (w << 10)] = pk(re[r], im[r]);
    __syncthreads();
    #pragma unroll
    for (int r = 0; r < R; ++r) {
        float2 v = unpk(sC[g | (h0 << 5) | (w << 6) | ((unsigned)r << 10)]);
        re[r] = v.x; im[r] = v.y;
    }
    REGSTAGE(1, cb2, sb2)  REGSTAGE(2, cb2, sb2)
    REGSTAGE(4, cb2, sb2)  REGSTAGE(8, cb2, sb2)   // hi bits 5-8; layer2 done
    // store at mapping A
    #pragma unroll
    for (int r = 0; r < R; ++r) {
        unsigned hi = h0 | (w << 1) | ((unsigned)r << 5);
        st[(size_t)hi * LO + lo0 + g] = pk(re[r], im[r]);
    }
}

// -------- K3: layer-2 bits 0-12 + fused |c|^2 * hS -> atomicAdd --------
__global__ __launch_bounds__(TPB, 4) void k_low2(
    const float* __restrict__ hS, const float* __restrict__ bet,
    const unsigned* __restrict__ st, float* __restrict__ out)
{
    __shared__ unsigned sC[LO];
    __shared__ float wsum[TPB / 64];
    const float cb = __cosf(bet[1]), sb = __sinf(bet[1]);
    const unsigned t = threadIdx.x, lane = t & 63u, wave = t >> 6;
    const size_t base = (size_t)blockIdx.x * LO;
    float re[R], im[R];

    #pragma unroll
    for (int r = 0; r < R; ++r) {
        float2 v = unpk(st[base + (unsigned)r * TPB + t]);
        re[r] = v.x; im[r] = v.y;
    }
    REGSTAGE(1, cb, sb)  REGSTAGE(2, cb, sb)
    REGSTAGE(4, cb, sb)  REGSTAGE(8, cb, sb)
    SHFLSTAGE(1,  cb, sb) SHFLSTAGE(2,  cb, sb)
    SHFLSTAGE(4,  cb, sb) SHFLSTAGE(8,  cb, sb)
    SHFLSTAGE(16, cb, sb) SHFLSTAGE(32, cb, sb)
    #pragma unroll
    for (int r = 0; r < R; ++r) sC[(unsigned)r * TPB + t] = pk(re[r], im[r]);
    __syncthreads();
    #pragma unroll
    for (int r = 0; r < R; ++r) {
        unsigned j = lane | ((unsigned)(r & 7) << 6) | (wave << 9) | ((unsigned)(r >> 3) << 12);
        float2 v = unpk(sC[j]); re[r] = v.x; im[r] = v.y;
    }
    REGSTAGE(1, cb, sb)  REGSTAGE(2, cb, sb)  REGSTAGE(4, cb, sb)
    float acc = 0.f;
    #pragma unroll
    for (int r = 0; r < R; ++r) {
        unsigned j = lane | ((unsigned)(r & 7) << 6) | (wave << 9) | ((unsigned)(r >> 3) << 12);
        acc = fmaf(re[r] * re[r] + im[r] * im[r], hS[base + j], acc);
    }
    #pragma unroll
    for (int off = 32; off >= 1; off >>= 1)
        acc += __shfl_down(acc, off, 64);
    if (lane == 0) wsum[wave] = acc;
    __syncthreads();
    if (t == 0) {
        float s = 0.f;
        #pragma unroll
        for (int w = 0; w < TPB / 64; ++w) s += wsum[w];
        unsafeAtomicAdd(out, s);   // native global_atomic_add_f32
    }
}

extern "C" void kernel_launch(void* const* d_in, const int* in_sizes, int n_in,
                              void* d_out, int out_size, void* d_ws, size_t ws_size,
                              hipStream_t stream)
{
    (void)in_sizes; (void)n_in; (void)out_size; (void)ws_size;
    const float* h   = (const float*)d_in[0];
    const float* hS  = (const float*)d_in[1];
    const float* gam = (const float*)d_in[2];
    const float* bet = (const float*)d_in[3];
    unsigned* st = (unsigned*)d_ws;       // 16 MB half2 state
    float* out   = (float*)d_out;

    k_init_low<<<dim3(NTOT / LO), dim3(TPB),  0, stream>>>(h, gam, bet, st, out);
    k_high    <<<dim3(LO / GRP),  dim3(TPB2), 0, stream>>>(h, gam, bet, st);
    k_low2    <<<dim3(NTOT / LO), dim3(TPB),  0, stream>>>(hS, bet, st, out);
}